// Round 3
// baseline (760.586 us; speedup 1.0000x reference)
//
#include <hip/hip_runtime.h>
#include <math.h>

#define NN 50000
#define NE 1600000

static inline int cdiv(int a, int b){ return (a + b - 1) / b; }

// ---------------- CSR build (counting sort by dst) ----------------

__global__ void k_hist(const int* __restrict__ dst, int* __restrict__ cnt, int e){
  int i = blockIdx.x*256 + threadIdx.x;
  if (i < e) atomicAdd(&cnt[dst[i]], 1);
}

__global__ void k_blocksum(const int* __restrict__ cnt, int* __restrict__ bsum, int n){
  __shared__ int sh[256];
  int t = threadIdx.x, i = blockIdx.x*256 + t;
  sh[t] = (i < n) ? cnt[i] : 0;
  __syncthreads();
  for (int o = 128; o > 0; o >>= 1){
    if (t < o) sh[t] += sh[t+o];
    __syncthreads();
  }
  if (t == 0) bsum[blockIdx.x] = sh[0];
}

__global__ void k_scan_bsum(const int* __restrict__ bsum, int* __restrict__ boff, int nb){
  __shared__ int sh[256];
  int t = threadIdx.x;
  int v = (t < nb) ? bsum[t] : 0;
  sh[t] = v; __syncthreads();
  for (int o = 1; o < 256; o <<= 1){
    int u = (t >= o) ? sh[t-o] : 0;
    __syncthreads();
    sh[t] += u;
    __syncthreads();
  }
  boff[t] = sh[t] - v;   // exclusive
}

__global__ void k_scan_final(const int* __restrict__ cnt, const int* __restrict__ boff,
                             int* __restrict__ row, int* __restrict__ cur, int n){
  __shared__ int sh[256];
  int t = threadIdx.x, i = blockIdx.x*256 + t;
  int v = (i < n) ? cnt[i] : 0;
  sh[t] = v; __syncthreads();
  for (int o = 1; o < 256; o <<= 1){
    int u = (t >= o) ? sh[t-o] : 0;
    __syncthreads();
    sh[t] += u;
    __syncthreads();
  }
  if (i < n){
    int val = sh[t] - v + boff[blockIdx.x];
    row[i] = val;
    cur[i] = val;
    if (i == n-1) row[n] = val + v;
  }
}

__global__ void k_scatter(const int* __restrict__ src, const int* __restrict__ dst,
                          const float* __restrict__ ew, int* __restrict__ cur,
                          int2* __restrict__ packed, int e){
  int i = blockIdx.x*256 + threadIdx.x;
  if (i >= e) return;
  int pos = atomicAdd(&cur[dst[i]], 1);
  packed[pos] = make_int2(src[i], __float_as_int(ew[i]));
}

// one wave per node: deg = 1 + sum(ew over in-edges); dinv = rsqrt(deg)
__global__ void k_deg_dinv(const int* __restrict__ row, const int2* __restrict__ packed,
                           float* __restrict__ dinv, int n){
  int tid = blockIdx.x*256 + threadIdx.x;
  int node = tid >> 6, lane = tid & 63;
  if (node >= n) return;
  int beg = row[node], end = row[node+1];
  float s = 0.f;
  for (int p = beg + lane; p < end; p += 64) s += __int_as_float(packed[p].y);
  for (int o = 32; o > 0; o >>= 1) s += __shfl_xor(s, o, 64);
  if (lane == 0) dinv[node] = rsqrtf(1.f + s);   // deg >= 1 always (self-loop)
}

// one wave per node: w_slot = ew * dinv[src] * dinv[node] (in place)
__global__ void k_nrm(const int* __restrict__ row, int2* __restrict__ packed,
                      const float* __restrict__ dinv, int n){
  int tid = blockIdx.x*256 + threadIdx.x;
  int node = tid >> 6, lane = tid & 63;
  if (node >= n) return;
  float di = dinv[node];
  int beg = row[node], end = row[node+1];
  for (int p = beg + lane; p < end; p += 64){
    int2 ed = packed[p];
    float w = __int_as_float(ed.y) * di * dinv[ed.x];
    ((float*)packed)[2*p + 1] = w;
  }
}

// ---------------- dense transforms ----------------

template<int FIN, bool RELU>
__global__ void k_xform64(const float* __restrict__ in, const float* __restrict__ W,
                          float* __restrict__ out, int n){
  __shared__ float Ws[FIN*64];
  for (int t = threadIdx.x; t < FIN*64; t += 256) Ws[t] = W[t];
  __syncthreads();
  int tid = blockIdx.x*256 + threadIdx.x;
  int node = tid >> 6, j = tid & 63;
  if (node >= n) return;
  float acc = 0.f;
  if constexpr ((FIN & 3) == 0){
    const float4* row4 = (const float4*)(in + (size_t)node*FIN);
    #pragma unroll
    for (int k4 = 0; k4 < FIN/4; ++k4){
      float4 v = row4[k4];
      if (RELU){ v.x=fmaxf(v.x,0.f); v.y=fmaxf(v.y,0.f); v.z=fmaxf(v.z,0.f); v.w=fmaxf(v.w,0.f); }
      acc = fmaf(v.x, Ws[(4*k4+0)*64 + j], acc);
      acc = fmaf(v.y, Ws[(4*k4+1)*64 + j], acc);
      acc = fmaf(v.z, Ws[(4*k4+2)*64 + j], acc);
      acc = fmaf(v.w, Ws[(4*k4+3)*64 + j], acc);
    }
  } else {
    const float* rowp = in + (size_t)node*FIN;
    #pragma unroll
    for (int k = 0; k < FIN; ++k){
      float v = rowp[k];
      if (RELU) v = fmaxf(v, 0.f);
      acc = fmaf(v, Ws[k*64 + j], acc);
    }
  }
  out[tid] = acc;
}

template<bool RELU>
__global__ void k_xform1(const float* __restrict__ in, const float* __restrict__ W,
                         float* __restrict__ out, int n){
  __shared__ float Ws[64];
  if (threadIdx.x < 64) Ws[threadIdx.x] = W[threadIdx.x];
  __syncthreads();
  int i = blockIdx.x*256 + threadIdx.x;
  if (i >= n) return;
  const float4* rowp = (const float4*)(in + (size_t)i*64);
  float acc = 0.f;
  #pragma unroll
  for (int k = 0; k < 16; ++k){
    float4 v = rowp[k];
    if (RELU){ v.x=fmaxf(v.x,0.f); v.y=fmaxf(v.y,0.f); v.z=fmaxf(v.z,0.f); v.w=fmaxf(v.w,0.f); }
    acc = fmaf(v.x, Ws[4*k+0], acc);
    acc = fmaf(v.y, Ws[4*k+1], acc);
    acc = fmaf(v.z, Ws[4*k+2], acc);
    acc = fmaf(v.w, Ws[4*k+3], acc);
  }
  out[i] = acc;
}

// ---------------- CSR aggregation (no atomics) ----------------

// one wave per dst node; lanes = 64 features.
// metadata: one coalesced 256B load per 32 edges, broadcast via v_readlane;
// per edge: one coalesced 256B gather of xw[src] -> 32 gathers in flight.
__global__ void k_agg64_csr(const int* __restrict__ row, const int2* __restrict__ packed,
                            const float* __restrict__ xw, const float* __restrict__ dinv,
                            const float* __restrict__ b, float* __restrict__ out, int n){
  int tid = blockIdx.x*256 + threadIdx.x;
  int node = tid >> 6, j = tid & 63;
  if (node >= n) return;
  float di = dinv[node];
  float acc = xw[tid]*(di*di) + b[j];
  int p = row[node], end = row[node+1];
  const int* pk = (const int*)packed;
  for (; p + 32 <= end; p += 32){
    int myv = pk[2*p + j];                 // 64 ints = 32 edges {src,w}, coalesced
    #pragma unroll
    for (int t = 0; t < 32; ++t){
      int   s = __builtin_amdgcn_readlane(myv, 2*t);
      float w = __int_as_float(__builtin_amdgcn_readlane(myv, 2*t+1));
      acc = fmaf(w, xw[s*64 + j], acc);
    }
  }
  int rem = end - p;
  if (rem > 0){
    int myv = (j < 2*rem) ? pk[2*p + j] : 0;
    for (int t = 0; t < rem; ++t){
      int   s = __builtin_amdgcn_readlane(myv, 2*t);
      float w = __int_as_float(__builtin_amdgcn_readlane(myv, 2*t+1));
      acc = fmaf(w, xw[s*64 + j], acc);
    }
  }
  out[tid] = acc;
}

// one wave per node, lane-parallel edges + butterfly reduce.
// then Linear(1,1) + build xin = cat(x, xsol)
__global__ void k_agg1_xsol(const int* __restrict__ row, const int2* __restrict__ packed,
                            const float* __restrict__ s0, const float* __restrict__ dinv,
                            const float* __restrict__ b, const float* __restrict__ Wl,
                            const float* __restrict__ bl, const float* __restrict__ x,
                            float* __restrict__ xsol, float* __restrict__ xin, int n){
  int tid = blockIdx.x*256 + threadIdx.x;
  int node = tid >> 6, lane = tid & 63;
  if (node >= n) return;
  int beg = row[node], end = row[node+1];
  float acc = 0.f;
  for (int p = beg + lane; p < end; p += 64){
    int2 ed = packed[p];
    acc = fmaf(__int_as_float(ed.y), s0[ed.x], acc);
  }
  for (int o = 32; o > 0; o >>= 1) acc += __shfl_xor(acc, o, 64);
  if (lane == 0){
    float di = dinv[node];
    float v = s0[node]*(di*di) + b[0] + acc;
    v = v*Wl[0] + bl[0];
    xsol[node] = v;
    float4 xv = ((const float4*)x)[node];
    xin[node*5+0] = xv.x;
    xin[node*5+1] = xv.y;
    xin[node*5+2] = xv.z;
    xin[node*5+3] = xv.w;
    xin[node*5+4] = v;
  }
}

// same, + sigmoid + gated residual combine
__global__ void k_agg1_final(const int* __restrict__ row, const int2* __restrict__ packed,
                             const float* __restrict__ s0, const float* __restrict__ dinv,
                             const float* __restrict__ b, const float* __restrict__ Wl,
                             const float* __restrict__ bl, const float* __restrict__ xsol,
                             const float* __restrict__ x, float* __restrict__ out, int n){
  int tid = blockIdx.x*256 + threadIdx.x;
  int node = tid >> 6, lane = tid & 63;
  if (node >= n) return;
  int beg = row[node], end = row[node+1];
  float acc = 0.f;
  for (int p = beg + lane; p < end; p += 64){
    int2 ed = packed[p];
    acc = fmaf(__int_as_float(ed.y), s0[ed.x], acc);
  }
  for (int o = 32; o > 0; o >>= 1) acc += __shfl_xor(acc, o, 64);
  if (lane == 0){
    float di = dinv[node];
    float g = s0[node]*(di*di) + b[0] + acc;
    g = g*Wl[0] + bl[0];
    float gamma = 1.f / (1.f + expf(-g));
    float xl = x[node*4+3];
    out[node]     = xl + gamma*(xsol[node] - xl);
    out[n + node] = gamma;
  }
}

// ---------------- launch ----------------

extern "C" void kernel_launch(void* const* d_in, const int* in_sizes, int n_in,
                              void* d_out, int out_size, void* d_ws, size_t ws_size,
                              hipStream_t stream){
  const float* x   = (const float*)d_in[0];
  const int*   ei  = (const int*)d_in[1];
  const float* ew  = (const float*)d_in[2];
  const float* oW0 = (const float*)d_in[3];
  const float* ob0 = (const float*)d_in[4];
  const float* oW1 = (const float*)d_in[5];
  const float* ob1 = (const float*)d_in[6];
  const float* oW2 = (const float*)d_in[7];
  const float* ob2 = (const float*)d_in[8];
  const float* oWl = (const float*)d_in[9];
  const float* obl = (const float*)d_in[10];
  const float* gW0 = (const float*)d_in[11];
  const float* gb0 = (const float*)d_in[12];
  const float* gW1 = (const float*)d_in[13];
  const float* gb1 = (const float*)d_in[14];
  const float* gW2 = (const float*)d_in[15];
  const float* gb2 = (const float*)d_in[16];
  const float* gWl = (const float*)d_in[17];
  const float* gbl = (const float*)d_in[18];

  const int n = NN, e = NE;
  const int* src = ei;
  const int* dst = ei + e;

  // workspace layout (packed first for 8B alignment)
  char* wsb = (char*)d_ws;
  int2*  packed = (int2*)wsb;                 wsb += (size_t)e*sizeof(int2);
  int*   cnt    = (int*)wsb;                  wsb += (size_t)n*4;
  int*   cur    = (int*)wsb;                  wsb += (size_t)n*4;
  int*   row    = (int*)wsb;                  wsb += (size_t)(n+1)*4;
  int*   bsum   = (int*)wsb;                  wsb += 256*4;
  int*   boff   = (int*)wsb;                  wsb += 256*4;
  float* dinv   = (float*)wsb;                wsb += (size_t)n*4;
  float* bufA   = (float*)wsb;                wsb += (size_t)n*64*4;
  float* bufB   = (float*)wsb;                wsb += (size_t)n*64*4;
  float* s0     = (float*)wsb;                wsb += (size_t)n*4;
  float* xsol   = (float*)wsb;                wsb += (size_t)n*4;
  float* xin    = (float*)wsb;                wsb += (size_t)n*5*4;

  dim3 b256(256);
  int gn   = cdiv(n, 256);        // 196
  int ge   = cdiv(e, 256);        // 6250
  int gw   = cdiv(n*64, 256);     // 12500 (wave-per-node kernels)

  // ---- CSR build + normalization (shared by all 6 convs) ----
  hipMemsetAsync(cnt, 0, (size_t)n*4, stream);
  k_hist      <<<ge, b256, 0, stream>>>(dst, cnt, e);
  k_blocksum  <<<gn, b256, 0, stream>>>(cnt, bsum, n);
  k_scan_bsum <<<1,  b256, 0, stream>>>(bsum, boff, gn);
  k_scan_final<<<gn, b256, 0, stream>>>(cnt, boff, row, cur, n);
  k_scatter   <<<ge, b256, 0, stream>>>(src, dst, ew, cur, packed, e);
  k_deg_dinv  <<<gw, b256, 0, stream>>>(row, packed, dinv, n);
  k_nrm       <<<gw, b256, 0, stream>>>(row, packed, dinv, n);

  // ---- optim tower: 4 -> 64 -> 64 -> 1, Linear(1,1) ----
  k_xform64<4,false><<<gw, b256, 0, stream>>>(x, oW0, bufA, n);
  k_agg64_csr       <<<gw, b256, 0, stream>>>(row, packed, bufA, dinv, ob0, bufB, n);
  k_xform64<64,true><<<gw, b256, 0, stream>>>(bufB, oW1, bufA, n);
  k_agg64_csr       <<<gw, b256, 0, stream>>>(row, packed, bufA, dinv, ob1, bufB, n);
  k_xform1<true>    <<<gn, b256, 0, stream>>>(bufB, oW2, s0, n);
  k_agg1_xsol       <<<gw, b256, 0, stream>>>(row, packed, s0, dinv, ob2, oWl, obl, x, xsol, xin, n);

  // ---- gamma tower: 5 -> 64 -> 64 -> 1, Linear(1,1), sigmoid ----
  k_xform64<5,false><<<gw, b256, 0, stream>>>(xin, gW0, bufA, n);
  k_agg64_csr       <<<gw, b256, 0, stream>>>(row, packed, bufA, dinv, gb0, bufB, n);
  k_xform64<64,true><<<gw, b256, 0, stream>>>(bufB, gW1, bufA, n);
  k_agg64_csr       <<<gw, b256, 0, stream>>>(row, packed, bufA, dinv, gb1, bufB, n);
  k_xform1<true>    <<<gn, b256, 0, stream>>>(bufB, gW2, s0, n);
  k_agg1_final      <<<gw, b256, 0, stream>>>(row, packed, s0, dinv, gb2, gWl, gbl, xsol, x, (float*)d_out, n);
}

// Round 4
// 662.326 us; speedup vs baseline: 1.1484x; 1.1484x over previous
//
#include <hip/hip_runtime.h>
#include <hip/hip_fp16.h>
#include <math.h>

#define NN 50000
#define NE 1600000
#define NBK 196          // buckets of 256 dst-nodes: cdiv(50000,256)
#define EPB 4096         // edges per block in k_bucket

static inline int cdiv(int a, int b){ return (a + b - 1) / b; }

// ---------------- CSR build ----------------

__global__ void k_hist(const int* __restrict__ dst, int* __restrict__ cnt, int e){
  int i = blockIdx.x*256 + threadIdx.x;
  if (i < e) atomicAdd(&cnt[dst[i]], 1);
}

__global__ void k_blocksum(const int* __restrict__ cnt, int* __restrict__ bsum, int n){
  __shared__ int sh[256];
  int t = threadIdx.x, i = blockIdx.x*256 + t;
  sh[t] = (i < n) ? cnt[i] : 0;
  __syncthreads();
  for (int o = 128; o > 0; o >>= 1){
    if (t < o) sh[t] += sh[t+o];
    __syncthreads();
  }
  if (t == 0) bsum[blockIdx.x] = sh[0];
}

__global__ void k_scan_bsum(const int* __restrict__ bsum, int* __restrict__ boff, int nb){
  __shared__ int sh[256];
  int t = threadIdx.x;
  int v = (t < nb) ? bsum[t] : 0;
  sh[t] = v; __syncthreads();
  for (int o = 1; o < 256; o <<= 1){
    int u = (t >= o) ? sh[t-o] : 0;
    __syncthreads();
    sh[t] += u;
    __syncthreads();
  }
  boff[t] = sh[t] - v;   // exclusive
}

__global__ void k_scan_final(const int* __restrict__ cnt, const int* __restrict__ boff,
                             int* __restrict__ row, int* __restrict__ cur, int n){
  __shared__ int sh[256];
  int t = threadIdx.x, i = blockIdx.x*256 + t;
  int v = (i < n) ? cnt[i] : 0;
  sh[t] = v; __syncthreads();
  for (int o = 1; o < 256; o <<= 1){
    int u = (t >= o) ? sh[t-o] : 0;
    __syncthreads();
    sh[t] += u;
    __syncthreads();
  }
  if (i < n){
    int val = sh[t] - v + boff[blockIdx.x];
    row[i] = val;
    cur[i] = val;
    if (i == n-1) row[n] = val + v;
  }
}

// bucket cursors start at the CSR offset of each 256-node bucket
__global__ void k_init_bcur(const int* __restrict__ row, int* __restrict__ bcur){
  int b = threadIdx.x;
  if (b < NBK) bcur[b] = row[b*256];
}

// phase A: bin edges by dst>>8 into bucket-contiguous regions (seL, dstL)
__global__ void k_bucket(const int* __restrict__ src, const int* __restrict__ dst,
                         const float* __restrict__ ew, int* __restrict__ bcur,
                         int2* __restrict__ seL, int* __restrict__ dstL, int e){
  __shared__ int h[NBK], base[NBK], cur[NBK];
  int t = threadIdx.x;
  for (int b = t; b < NBK; b += 256){ h[b] = 0; cur[b] = 0; }
  __syncthreads();
  int beg = blockIdx.x*EPB;
  int end = min(beg + EPB, e);
  for (int i = beg + t; i < end; i += 256)
    atomicAdd(&h[dst[i] >> 8], 1);
  __syncthreads();
  for (int b = t; b < NBK; b += 256)
    if (h[b] > 0) base[b] = atomicAdd(&bcur[b], h[b]);
  __syncthreads();
  for (int i = beg + t; i < end; i += 256){
    int d = dst[i];
    int b = d >> 8;
    int pos = base[b] + atomicAdd(&cur[b], 1);
    seL[pos]  = make_int2(src[i], __float_as_int(ew[i]));
    dstL[pos] = d;
  }
}

// phase B: exact-position scatter over the bucket-ordered stream
// (packed writes confined to a rolling ~64KB CSR window -> L2-coalesced)
__global__ void k_scatter2(const int2* __restrict__ seL, const int* __restrict__ dstL,
                           int* __restrict__ cur, int2* __restrict__ packed, int e){
  int i = blockIdx.x*256 + threadIdx.x;
  if (i >= e) return;
  int pos = atomicAdd(&cur[dstL[i]], 1);
  packed[pos] = seL[i];
}

// one wave per node: deg = 1 + sum(ew); dinv = rsqrt(deg)
__global__ void k_deg_dinv(const int* __restrict__ row, const int2* __restrict__ packed,
                           float* __restrict__ dinv, int n){
  int tid = blockIdx.x*256 + threadIdx.x;
  int node = tid >> 6, lane = tid & 63;
  if (node >= n) return;
  int beg = row[node], end = row[node+1];
  float s = 0.f;
  for (int p = beg + lane; p < end; p += 64) s += __int_as_float(packed[p].y);
  for (int o = 32; o > 0; o >>= 1) s += __shfl_xor(s, o, 64);
  if (lane == 0) dinv[node] = rsqrtf(1.f + s);
}

// one wave per node: w_slot = ew * dinv[src] * dinv[node]
__global__ void k_nrm(const int* __restrict__ row, int2* __restrict__ packed,
                      const float* __restrict__ dinv, int n){
  int tid = blockIdx.x*256 + threadIdx.x;
  int node = tid >> 6, lane = tid & 63;
  if (node >= n) return;
  float di = dinv[node];
  int beg = row[node], end = row[node+1];
  for (int p = beg + lane; p < end; p += 64){
    int2 ed = packed[p];
    ((float*)packed)[2*p + 1] = __int_as_float(ed.y) * di * dinv[ed.x];
  }
}

// ---------------- dense transforms ----------------

// out (fp16) [n,64] = act(in[n,FIN]) @ W[FIN,64]
template<int FIN, bool RELU>
__global__ void k_xform64(const float* __restrict__ in, const float* __restrict__ W,
                          __half* __restrict__ out, int n){
  __shared__ float Ws[FIN*64];
  for (int t = threadIdx.x; t < FIN*64; t += 256) Ws[t] = W[t];
  __syncthreads();
  int tid = blockIdx.x*256 + threadIdx.x;
  int node = tid >> 6, j = tid & 63;
  if (node >= n) return;
  float acc = 0.f;
  if constexpr ((FIN & 3) == 0){
    const float4* row4 = (const float4*)(in + (size_t)node*FIN);
    #pragma unroll
    for (int k4 = 0; k4 < FIN/4; ++k4){
      float4 v = row4[k4];
      if (RELU){ v.x=fmaxf(v.x,0.f); v.y=fmaxf(v.y,0.f); v.z=fmaxf(v.z,0.f); v.w=fmaxf(v.w,0.f); }
      acc = fmaf(v.x, Ws[(4*k4+0)*64 + j], acc);
      acc = fmaf(v.y, Ws[(4*k4+1)*64 + j], acc);
      acc = fmaf(v.z, Ws[(4*k4+2)*64 + j], acc);
      acc = fmaf(v.w, Ws[(4*k4+3)*64 + j], acc);
    }
  } else {
    const float* rowp = in + (size_t)node*FIN;
    #pragma unroll
    for (int k = 0; k < FIN; ++k){
      float v = rowp[k];
      if (RELU) v = fmaxf(v, 0.f);
      acc = fmaf(v, Ws[k*64 + j], acc);
    }
  }
  out[tid] = __float2half(acc);
}

template<bool RELU>
__global__ void k_xform1(const float* __restrict__ in, const float* __restrict__ W,
                         float* __restrict__ out, int n){
  __shared__ float Ws[64];
  if (threadIdx.x < 64) Ws[threadIdx.x] = W[threadIdx.x];
  __syncthreads();
  int i = blockIdx.x*256 + threadIdx.x;
  if (i >= n) return;
  const float4* rowp = (const float4*)(in + (size_t)i*64);
  float acc = 0.f;
  #pragma unroll
  for (int k = 0; k < 16; ++k){
    float4 v = rowp[k];
    if (RELU){ v.x=fmaxf(v.x,0.f); v.y=fmaxf(v.y,0.f); v.z=fmaxf(v.z,0.f); v.w=fmaxf(v.w,0.f); }
    acc = fmaf(v.x, Ws[4*k+0], acc);
    acc = fmaf(v.y, Ws[4*k+1], acc);
    acc = fmaf(v.z, Ws[4*k+2], acc);
    acc = fmaf(v.w, Ws[4*k+3], acc);
  }
  out[i] = acc;
}

// ---------------- CSR aggregation ----------------

// one wave per dst node; lanes = 64 features; fp16 gather, fp32 accumulate
__global__ void k_agg64_csr(const int* __restrict__ row, const int2* __restrict__ packed,
                            const __half* __restrict__ xw, const float* __restrict__ dinv,
                            const float* __restrict__ b, float* __restrict__ out, int n){
  int tid = blockIdx.x*256 + threadIdx.x;
  int node = tid >> 6, j = tid & 63;
  if (node >= n) return;
  float di = dinv[node];
  float acc = __half2float(xw[tid])*(di*di) + b[j];
  int p = row[node], end = row[node+1];
  const int* pk = (const int*)packed;
  for (; p + 32 <= end; p += 32){
    int myv = pk[2*p + j];                 // 32 edges' {src,w}, coalesced
    #pragma unroll
    for (int t = 0; t < 32; ++t){
      int   s = __builtin_amdgcn_readlane(myv, 2*t);
      float w = __int_as_float(__builtin_amdgcn_readlane(myv, 2*t+1));
      acc = fmaf(w, __half2float(xw[s*64 + j]), acc);
    }
  }
  int rem = end - p;
  if (rem > 0){
    int myv = (j < 2*rem) ? pk[2*p + j] : 0;
    for (int t = 0; t < rem; ++t){
      int   s = __builtin_amdgcn_readlane(myv, 2*t);
      float w = __int_as_float(__builtin_amdgcn_readlane(myv, 2*t+1));
      acc = fmaf(w, __half2float(xw[s*64 + j]), acc);
    }
  }
  out[tid] = acc;
}

// scalar agg (wave per node) + Linear(1,1) + build xin = cat(x, xsol)
__global__ void k_agg1_xsol(const int* __restrict__ row, const int2* __restrict__ packed,
                            const float* __restrict__ s0, const float* __restrict__ dinv,
                            const float* __restrict__ b, const float* __restrict__ Wl,
                            const float* __restrict__ bl, const float* __restrict__ x,
                            float* __restrict__ xsol, float* __restrict__ xin, int n){
  int tid = blockIdx.x*256 + threadIdx.x;
  int node = tid >> 6, lane = tid & 63;
  if (node >= n) return;
  int beg = row[node], end = row[node+1];
  float acc = 0.f;
  for (int p = beg + lane; p < end; p += 64){
    int2 ed = packed[p];
    acc = fmaf(__int_as_float(ed.y), s0[ed.x], acc);
  }
  for (int o = 32; o > 0; o >>= 1) acc += __shfl_xor(acc, o, 64);
  if (lane == 0){
    float di = dinv[node];
    float v = s0[node]*(di*di) + b[0] + acc;
    v = v*Wl[0] + bl[0];
    xsol[node] = v;
    float4 xv = ((const float4*)x)[node];
    xin[node*5+0] = xv.x;
    xin[node*5+1] = xv.y;
    xin[node*5+2] = xv.z;
    xin[node*5+3] = xv.w;
    xin[node*5+4] = v;
  }
}

// scalar agg + Linear(1,1) + sigmoid + gated residual combine
__global__ void k_agg1_final(const int* __restrict__ row, const int2* __restrict__ packed,
                             const float* __restrict__ s0, const float* __restrict__ dinv,
                             const float* __restrict__ b, const float* __restrict__ Wl,
                             const float* __restrict__ bl, const float* __restrict__ xsol,
                             const float* __restrict__ x, float* __restrict__ out, int n){
  int tid = blockIdx.x*256 + threadIdx.x;
  int node = tid >> 6, lane = tid & 63;
  if (node >= n) return;
  int beg = row[node], end = row[node+1];
  float acc = 0.f;
  for (int p = beg + lane; p < end; p += 64){
    int2 ed = packed[p];
    acc = fmaf(__int_as_float(ed.y), s0[ed.x], acc);
  }
  for (int o = 32; o > 0; o >>= 1) acc += __shfl_xor(acc, o, 64);
  if (lane == 0){
    float di = dinv[node];
    float g = s0[node]*(di*di) + b[0] + acc;
    g = g*Wl[0] + bl[0];
    float gamma = 1.f / (1.f + expf(-g));
    float xl = x[node*4+3];
    out[node]     = xl + gamma*(xsol[node] - xl);
    out[n + node] = gamma;
  }
}

// ---------------- launch ----------------

extern "C" void kernel_launch(void* const* d_in, const int* in_sizes, int n_in,
                              void* d_out, int out_size, void* d_ws, size_t ws_size,
                              hipStream_t stream){
  const float* x   = (const float*)d_in[0];
  const int*   ei  = (const int*)d_in[1];
  const float* ew  = (const float*)d_in[2];
  const float* oW0 = (const float*)d_in[3];
  const float* ob0 = (const float*)d_in[4];
  const float* oW1 = (const float*)d_in[5];
  const float* ob1 = (const float*)d_in[6];
  const float* oW2 = (const float*)d_in[7];
  const float* ob2 = (const float*)d_in[8];
  const float* oWl = (const float*)d_in[9];
  const float* obl = (const float*)d_in[10];
  const float* gW0 = (const float*)d_in[11];
  const float* gb0 = (const float*)d_in[12];
  const float* gW1 = (const float*)d_in[13];
  const float* gb1 = (const float*)d_in[14];
  const float* gW2 = (const float*)d_in[15];
  const float* gb2 = (const float*)d_in[16];
  const float* gWl = (const float*)d_in[17];
  const float* gbl = (const float*)d_in[18];

  const int n = NN, e = NE;
  const int* src = ei;
  const int* dst = ei + e;

  // workspace layout (8B-aligned blocks first)
  char* wsb = (char*)d_ws;
  int2*  packed = (int2*)wsb;      wsb += (size_t)e*sizeof(int2);      // 12.8 MB
  float* bufB   = (float*)wsb;     wsb += (size_t)n*64*4;              // 12.8 MB
  __half* bufA  = (__half*)wsb;    wsb += (size_t)n*64*2;              // 6.4 MB
  int*   cnt    = (int*)wsb;       wsb += (size_t)n*4;
  int*   cur    = (int*)wsb;       wsb += (size_t)n*4;
  int*   row    = (int*)wsb;       wsb += (size_t)(n+1)*4;
  int*   bsum   = (int*)wsb;       wsb += 256*4;
  int*   boff   = (int*)wsb;       wsb += 256*4;
  int*   bcur   = (int*)wsb;       wsb += 256*4;
  float* dinv   = (float*)wsb;     wsb += (size_t)n*4;
  float* s0     = (float*)wsb;     wsb += (size_t)n*4;
  float* xsol   = (float*)wsb;     wsb += (size_t)n*4;
  float* xin    = (float*)wsb;     wsb += (size_t)n*5*4;

  // build-time aliases (dead once towers start): seL over bufB, dstL over bufA
  int2* seL  = (int2*)bufB;        // needs e*8   = 12.8 MB <= 12.8 MB
  int*  dstL = (int*)bufA;         // needs e*4   =  6.4 MB <=  6.4 MB

  dim3 b256(256);
  int gn   = cdiv(n, 256);        // 196
  int ge   = cdiv(e, 256);        // 6250
  int gw   = cdiv(n*64, 256);     // 12500
  int gb   = cdiv(e, EPB);        // 391

  // ---- CSR build + normalization (shared by all 6 convs) ----
  hipMemsetAsync(cnt, 0, (size_t)n*4, stream);
  k_hist      <<<ge, b256, 0, stream>>>(dst, cnt, e);
  k_blocksum  <<<gn, b256, 0, stream>>>(cnt, bsum, n);
  k_scan_bsum <<<1,  b256, 0, stream>>>(bsum, boff, gn);
  k_scan_final<<<gn, b256, 0, stream>>>(cnt, boff, row, cur, n);
  k_init_bcur <<<1,  b256, 0, stream>>>(row, bcur);
  k_bucket    <<<gb, b256, 0, stream>>>(src, dst, ew, bcur, seL, dstL, e);
  k_scatter2  <<<ge, b256, 0, stream>>>(seL, dstL, cur, packed, e);
  k_deg_dinv  <<<gw, b256, 0, stream>>>(row, packed, dinv, n);
  k_nrm       <<<gw, b256, 0, stream>>>(row, packed, dinv, n);

  // ---- optim tower: 4 -> 64 -> 64 -> 1, Linear(1,1) ----
  k_xform64<4,false><<<gw, b256, 0, stream>>>(x, oW0, bufA, n);
  k_agg64_csr       <<<gw, b256, 0, stream>>>(row, packed, bufA, dinv, ob0, bufB, n);
  k_xform64<64,true><<<gw, b256, 0, stream>>>(bufB, oW1, bufA, n);
  k_agg64_csr       <<<gw, b256, 0, stream>>>(row, packed, bufA, dinv, ob1, bufB, n);
  k_xform1<true>    <<<gn, b256, 0, stream>>>(bufB, oW2, s0, n);
  k_agg1_xsol       <<<gw, b256, 0, stream>>>(row, packed, s0, dinv, ob2, oWl, obl, x, xsol, xin, n);

  // ---- gamma tower: 5 -> 64 -> 64 -> 1, Linear(1,1), sigmoid ----
  k_xform64<5,false><<<gw, b256, 0, stream>>>(xin, gW0, bufA, n);
  k_agg64_csr       <<<gw, b256, 0, stream>>>(row, packed, bufA, dinv, gb0, bufB, n);
  k_xform64<64,true><<<gw, b256, 0, stream>>>(bufB, gW1, bufA, n);
  k_agg64_csr       <<<gw, b256, 0, stream>>>(row, packed, bufA, dinv, gb1, bufB, n);
  k_xform1<true>    <<<gn, b256, 0, stream>>>(bufB, gW2, s0, n);
  k_agg1_final      <<<gw, b256, 0, stream>>>(row, packed, s0, dinv, gb2, gWl, gbl, xsol, x, (float*)d_out, n);
}

// Round 5
// 640.404 us; speedup vs baseline: 1.1877x; 1.0342x over previous
//
#include <hip/hip_runtime.h>
#include <hip/hip_fp16.h>
#include <math.h>

#define NN 50000
#define NE 1600000
#define NBK 196          // buckets of 256 dst-nodes: cdiv(50000,256)
#define EPB 4096         // edges per block in bucket kernels

static inline int cdiv(int a, int b){ return (a + b - 1) / b; }

// ---------------- CSR build: bucket counting (LDS hist, few global atomics) ----------------

__global__ void k_bcount(const int* __restrict__ dst, int* __restrict__ bcnt, int e){
  __shared__ int h[NBK];
  int t = threadIdx.x;
  for (int b = t; b < NBK; b += 256) h[b] = 0;
  __syncthreads();
  int beg = blockIdx.x*EPB, end = min(beg + EPB, e);
  for (int i = beg + t; i < end; i += 256) atomicAdd(&h[dst[i] >> 8], 1);
  __syncthreads();
  for (int b = t; b < NBK; b += 256) if (h[b]) atomicAdd(&bcnt[b], h[b]);
}

// single block: exclusive scan of 196 bucket counts -> boff[0..196]; init bcur; row[n]=e
__global__ void k_scan_bcnt(const int* __restrict__ bcnt, int* __restrict__ boff,
                            int* __restrict__ bcur, int* __restrict__ row){
  __shared__ int sh[256];
  int t = threadIdx.x;
  int v = (t < NBK) ? bcnt[t] : 0;
  sh[t] = v; __syncthreads();
  for (int o = 1; o < 256; o <<= 1){
    int u = (t >= o) ? sh[t-o] : 0;
    __syncthreads();
    sh[t] += u;
    __syncthreads();
  }
  int ex = sh[t] - v;
  if (t <= NBK) boff[t] = ex;          // boff[NBK] == e
  if (t <  NBK) bcur[t] = ex;
  if (t == 0)   row[NN] = NE;
}

// phase A: bin edges by dst>>8; pack dlow into src high bits (src < 65536)
__global__ void k_bucket(const int* __restrict__ src, const int* __restrict__ dst,
                         const float* __restrict__ ew, int* __restrict__ bcur,
                         int2* __restrict__ seL, int e){
  __shared__ int h[NBK], base[NBK], cur[NBK];
  int t = threadIdx.x;
  for (int b = t; b < NBK; b += 256){ h[b] = 0; cur[b] = 0; }
  __syncthreads();
  int beg = blockIdx.x*EPB, end = min(beg + EPB, e);
  for (int i = beg + t; i < end; i += 256) atomicAdd(&h[dst[i] >> 8], 1);
  __syncthreads();
  for (int b = t; b < NBK; b += 256)
    if (h[b] > 0) base[b] = atomicAdd(&bcur[b], h[b]);
  __syncthreads();
  for (int i = beg + t; i < end; i += 256){
    int d = dst[i], b = d >> 8;
    int pos = base[b] + atomicAdd(&cur[b], 1);
    seL[pos] = make_int2(((d & 255) << 16) | src[i], __float_as_int(ew[i]));
  }
}

// phase B: one block per bucket. Per-node hist+scan+scatter+deg ALL in LDS.
// packed writes confined to this bucket's contiguous ~65KB window.
__global__ void k_csr_bucket(const int* __restrict__ boff, const int2* __restrict__ seL,
                             int* __restrict__ row, int2* __restrict__ packed,
                             float* __restrict__ dinv, int n){
  __shared__ int hist[256], sh[256], cur[256];
  __shared__ float wsum[256];
  int b = blockIdx.x, t = threadIdx.x;
  int ebeg = boff[b], eend = boff[b+1];
  hist[t] = 0; wsum[t] = 0.f;
  __syncthreads();
  for (int i = ebeg + t; i < eend; i += 256)
    atomicAdd(&hist[seL[i].x >> 16], 1);
  __syncthreads();
  int v = hist[t];
  sh[t] = v; __syncthreads();
  for (int o = 1; o < 256; o <<= 1){
    int u = (t >= o) ? sh[t-o] : 0;
    __syncthreads();
    sh[t] += u;
    __syncthreads();
  }
  int rowv = ebeg + sh[t] - v;
  int node = b*256 + t;
  if (node < n) row[node] = rowv;
  cur[t] = rowv;
  __syncthreads();
  for (int i = ebeg + t; i < eend; i += 256){
    int2 u = seL[i];
    int d = u.x >> 16;
    int pos = atomicAdd(&cur[d], 1);
    packed[pos] = make_int2(u.x & 0xFFFF, u.y);
    atomicAdd(&wsum[d], __int_as_float(u.y));
  }
  __syncthreads();
  if (node < n) dinv[node] = rsqrtf(1.f + wsum[t]);   // deg >= 1 (self-loop)
}

// one wave per node: w_slot = ew * dinv[src] * dinv[node]
__global__ void k_nrm(const int* __restrict__ row, int2* __restrict__ packed,
                      const float* __restrict__ dinv, int n){
  int tid = blockIdx.x*256 + threadIdx.x;
  int node = tid >> 6, lane = tid & 63;
  if (node >= n) return;
  float di = dinv[node];
  int beg = row[node], end = row[node+1];
  for (int p = beg + lane; p < end; p += 64){
    int2 ed = packed[p];
    ((float*)packed)[2*p + 1] = __int_as_float(ed.y) * di * dinv[ed.x];
  }
}

// ---------------- dense transforms ----------------

// out (fp16, half-split layout xwh[2][n][32]) = act(in[n,FIN]) @ W[FIN,64]
template<int FIN, bool RELU>
__global__ void k_xform64(const float* __restrict__ in, const float* __restrict__ W,
                          __half* __restrict__ out, int n){
  __shared__ float Ws[FIN*64];
  for (int t = threadIdx.x; t < FIN*64; t += 256) Ws[t] = W[t];
  __syncthreads();
  int tid = blockIdx.x*256 + threadIdx.x;
  int node = tid >> 6, j = tid & 63;
  if (node >= n) return;
  float acc = 0.f;
  if constexpr ((FIN & 3) == 0){
    const float4* row4 = (const float4*)(in + (size_t)node*FIN);
    #pragma unroll
    for (int k4 = 0; k4 < FIN/4; ++k4){
      float4 v = row4[k4];
      if (RELU){ v.x=fmaxf(v.x,0.f); v.y=fmaxf(v.y,0.f); v.z=fmaxf(v.z,0.f); v.w=fmaxf(v.w,0.f); }
      acc = fmaf(v.x, Ws[(4*k4+0)*64 + j], acc);
      acc = fmaf(v.y, Ws[(4*k4+1)*64 + j], acc);
      acc = fmaf(v.z, Ws[(4*k4+2)*64 + j], acc);
      acc = fmaf(v.w, Ws[(4*k4+3)*64 + j], acc);
    }
  } else {
    const float* rowp = in + (size_t)node*FIN;
    #pragma unroll
    for (int k = 0; k < FIN; ++k){
      float v = rowp[k];
      if (RELU) v = fmaxf(v, 0.f);
      acc = fmaf(v, Ws[k*64 + j], acc);
    }
  }
  out[((size_t)(j >> 5)*n + node)*32 + (j & 31)] = __float2half(acc);
}

template<bool RELU>
__global__ void k_xform1(const float* __restrict__ in, const float* __restrict__ W,
                         float* __restrict__ out, int n){
  __shared__ float Ws[64];
  if (threadIdx.x < 64) Ws[threadIdx.x] = W[threadIdx.x];
  __syncthreads();
  int i = blockIdx.x*256 + threadIdx.x;
  if (i >= n) return;
  const float4* rowp = (const float4*)(in + (size_t)i*64);
  float acc = 0.f;
  #pragma unroll
  for (int k = 0; k < 16; ++k){
    float4 v = rowp[k];
    if (RELU){ v.x=fmaxf(v.x,0.f); v.y=fmaxf(v.y,0.f); v.z=fmaxf(v.z,0.f); v.w=fmaxf(v.w,0.f); }
    acc = fmaf(v.x, Ws[4*k+0], acc);
    acc = fmaf(v.y, Ws[4*k+1], acc);
    acc = fmaf(v.z, Ws[4*k+2], acc);
    acc = fmaf(v.w, Ws[4*k+3], acc);
  }
  out[i] = acc;
}

// ---------------- CSR aggregation: feature-half pass, L2-resident gather ----------------

// one wave per node; lanes 0-31 = edge pair's even edge (features 0-31 of this half),
// lanes 32-63 = odd edge. Gather working set = n*32*2B = 3.2MB < 4MiB L2.
// packed metadata streamed nontemporally to avoid evicting the feature table.
template<int PASS>
__global__ void k_agg64h(const int* __restrict__ row, const int2* __restrict__ packed,
                         const __half* __restrict__ xw, const float* __restrict__ dinv,
                         const float* __restrict__ b, float* __restrict__ out, int n){
  int tid = blockIdx.x*256 + threadIdx.x;
  int node = tid >> 6, lane = tid & 63;
  if (node >= n) return;
  int f = lane & 31, ep = lane >> 5;
  const __half* xh = xw + (size_t)PASS*n*32;
  const int* pk = (const int*)packed;
  float acc = 0.f;
  int p = row[node], end = row[node+1];
  for (; p + 32 <= end; p += 32){
    int myv = __builtin_nontemporal_load(&pk[2*p + lane]);   // 32 edges {src,w}
    #pragma unroll
    for (int t = 0; t < 16; ++t){
      int   s0 = __builtin_amdgcn_readlane(myv, 4*t);
      float w0 = __int_as_float(__builtin_amdgcn_readlane(myv, 4*t+1));
      int   s1 = __builtin_amdgcn_readlane(myv, 4*t+2);
      float w1 = __int_as_float(__builtin_amdgcn_readlane(myv, 4*t+3));
      int s = ep ? s1 : s0;
      float w = ep ? w1 : w0;
      acc = fmaf(w, __half2float(xh[s*32 + f]), acc);
    }
  }
  int rem = end - p;
  if (rem > 0){
    int myv = (lane < 2*rem) ? pk[2*p + lane] : 0;   // OOB lanes: s=0,w=0 (harmless)
    for (int t = 0; 2*t < rem; ++t){
      int   s0 = __builtin_amdgcn_readlane(myv, 4*t);
      float w0 = __int_as_float(__builtin_amdgcn_readlane(myv, 4*t+1));
      int   s1 = __builtin_amdgcn_readlane(myv, 4*t+2);
      float w1 = __int_as_float(__builtin_amdgcn_readlane(myv, 4*t+3));
      int s = ep ? s1 : s0;
      float w = ep ? w1 : w0;
      acc = fmaf(w, __half2float(xh[s*32 + f]), acc);
    }
  }
  acc += __shfl_xor(acc, 32, 64);                    // combine even/odd edge partials
  if (ep == 0){
    float di = dinv[node];
    float tot = acc + __half2float(xh[(size_t)node*32 + f])*(di*di) + b[PASS*32 + f];
    __builtin_nontemporal_store(tot, &out[(size_t)node*64 + PASS*32 + f]);
  }
}

// scalar agg (wave per node) + Linear(1,1) + build xin = cat(x, xsol)
__global__ void k_agg1_xsol(const int* __restrict__ row, const int2* __restrict__ packed,
                            const float* __restrict__ s0, const float* __restrict__ dinv,
                            const float* __restrict__ b, const float* __restrict__ Wl,
                            const float* __restrict__ bl, const float* __restrict__ x,
                            float* __restrict__ xsol, float* __restrict__ xin, int n){
  int tid = blockIdx.x*256 + threadIdx.x;
  int node = tid >> 6, lane = tid & 63;
  if (node >= n) return;
  int beg = row[node], end = row[node+1];
  float acc = 0.f;
  for (int p = beg + lane; p < end; p += 64){
    int2 ed = packed[p];
    acc = fmaf(__int_as_float(ed.y), s0[ed.x], acc);
  }
  for (int o = 32; o > 0; o >>= 1) acc += __shfl_xor(acc, o, 64);
  if (lane == 0){
    float di = dinv[node];
    float v = s0[node]*(di*di) + b[0] + acc;
    v = v*Wl[0] + bl[0];
    xsol[node] = v;
    float4 xv = ((const float4*)x)[node];
    xin[node*5+0] = xv.x;
    xin[node*5+1] = xv.y;
    xin[node*5+2] = xv.z;
    xin[node*5+3] = xv.w;
    xin[node*5+4] = v;
  }
}

// scalar agg + Linear(1,1) + sigmoid + gated residual combine
__global__ void k_agg1_final(const int* __restrict__ row, const int2* __restrict__ packed,
                             const float* __restrict__ s0, const float* __restrict__ dinv,
                             const float* __restrict__ b, const float* __restrict__ Wl,
                             const float* __restrict__ bl, const float* __restrict__ xsol,
                             const float* __restrict__ x, float* __restrict__ out, int n){
  int tid = blockIdx.x*256 + threadIdx.x;
  int node = tid >> 6, lane = tid & 63;
  if (node >= n) return;
  int beg = row[node], end = row[node+1];
  float acc = 0.f;
  for (int p = beg + lane; p < end; p += 64){
    int2 ed = packed[p];
    acc = fmaf(__int_as_float(ed.y), s0[ed.x], acc);
  }
  for (int o = 32; o > 0; o >>= 1) acc += __shfl_xor(acc, o, 64);
  if (lane == 0){
    float di = dinv[node];
    float g = s0[node]*(di*di) + b[0] + acc;
    g = g*Wl[0] + bl[0];
    float gamma = 1.f / (1.f + expf(-g));
    float xl = x[node*4+3];
    out[node]     = xl + gamma*(xsol[node] - xl);
    out[n + node] = gamma;
  }
}

// ---------------- launch ----------------

extern "C" void kernel_launch(void* const* d_in, const int* in_sizes, int n_in,
                              void* d_out, int out_size, void* d_ws, size_t ws_size,
                              hipStream_t stream){
  const float* x   = (const float*)d_in[0];
  const int*   ei  = (const int*)d_in[1];
  const float* ew  = (const float*)d_in[2];
  const float* oW0 = (const float*)d_in[3];
  const float* ob0 = (const float*)d_in[4];
  const float* oW1 = (const float*)d_in[5];
  const float* ob1 = (const float*)d_in[6];
  const float* oW2 = (const float*)d_in[7];
  const float* ob2 = (const float*)d_in[8];
  const float* oWl = (const float*)d_in[9];
  const float* obl = (const float*)d_in[10];
  const float* gW0 = (const float*)d_in[11];
  const float* gb0 = (const float*)d_in[12];
  const float* gW1 = (const float*)d_in[13];
  const float* gb1 = (const float*)d_in[14];
  const float* gW2 = (const float*)d_in[15];
  const float* gb2 = (const float*)d_in[16];
  const float* gWl = (const float*)d_in[17];
  const float* gbl = (const float*)d_in[18];

  const int n = NN, e = NE;
  const int* src = ei;
  const int* dst = ei + e;

  // workspace layout (8B-aligned blocks first)
  char* wsb = (char*)d_ws;
  int2*  packed = (int2*)wsb;      wsb += (size_t)e*sizeof(int2);      // 12.8 MB
  float* bufB   = (float*)wsb;     wsb += (size_t)n*64*4;              // 12.8 MB
  __half* bufA  = (__half*)wsb;    wsb += (size_t)n*64*2;              // 6.4 MB (xwh[2][n][32])
  int*   row    = (int*)wsb;       wsb += (size_t)(n+1)*4;
  int*   bcnt   = (int*)wsb;       wsb += 256*4;
  int*   boff   = (int*)wsb;       wsb += 256*4;
  int*   bcur   = (int*)wsb;       wsb += 256*4;
  float* dinv   = (float*)wsb;     wsb += (size_t)n*4;
  float* s0     = (float*)wsb;     wsb += (size_t)n*4;
  float* xsol   = (float*)wsb;     wsb += (size_t)n*4;
  float* xin    = (float*)wsb;     wsb += (size_t)n*5*4;

  // build-time alias (dead once towers start): seL over bufB
  int2* seL = (int2*)bufB;         // e*8 = 12.8 MB <= 12.8 MB

  dim3 b256(256);
  int gn = cdiv(n, 256);           // 196
  int gw = cdiv(n*64, 256);        // 12500 (wave-per-node kernels)
  int gb = cdiv(e, EPB);           // 391

  // ---- CSR build + normalization (shared by all 6 convs) ----
  hipMemsetAsync(bcnt, 0, 256*4, stream);
  k_bcount    <<<gb,  b256, 0, stream>>>(dst, bcnt, e);
  k_scan_bcnt <<<1,   b256, 0, stream>>>(bcnt, boff, bcur, row);
  k_bucket    <<<gb,  b256, 0, stream>>>(src, dst, ew, bcur, seL, e);
  k_csr_bucket<<<NBK, b256, 0, stream>>>(boff, seL, row, packed, dinv, n);
  k_nrm       <<<gw,  b256, 0, stream>>>(row, packed, dinv, n);

  // ---- optim tower: 4 -> 64 -> 64 -> 1, Linear(1,1) ----
  k_xform64<4,false><<<gw, b256, 0, stream>>>(x, oW0, bufA, n);
  k_agg64h<0>       <<<gw, b256, 0, stream>>>(row, packed, bufA, dinv, ob0, bufB, n);
  k_agg64h<1>       <<<gw, b256, 0, stream>>>(row, packed, bufA, dinv, ob0, bufB, n);
  k_xform64<64,true><<<gw, b256, 0, stream>>>(bufB, oW1, bufA, n);
  k_agg64h<0>       <<<gw, b256, 0, stream>>>(row, packed, bufA, dinv, ob1, bufB, n);
  k_agg64h<1>       <<<gw, b256, 0, stream>>>(row, packed, bufA, dinv, ob1, bufB, n);
  k_xform1<true>    <<<gn, b256, 0, stream>>>(bufB, oW2, s0, n);
  k_agg1_xsol       <<<gw, b256, 0, stream>>>(row, packed, s0, dinv, ob2, oWl, obl, x, xsol, xin, n);

  // ---- gamma tower: 5 -> 64 -> 64 -> 1, Linear(1,1), sigmoid ----
  k_xform64<5,false><<<gw, b256, 0, stream>>>(xin, gW0, bufA, n);
  k_agg64h<0>       <<<gw, b256, 0, stream>>>(row, packed, bufA, dinv, gb0, bufB, n);
  k_agg64h<1>       <<<gw, b256, 0, stream>>>(row, packed, bufA, dinv, gb0, bufB, n);
  k_xform64<64,true><<<gw, b256, 0, stream>>>(bufB, gW1, bufA, n);
  k_agg64h<0>       <<<gw, b256, 0, stream>>>(row, packed, bufA, dinv, gb1, bufB, n);
  k_agg64h<1>       <<<gw, b256, 0, stream>>>(row, packed, bufA, dinv, gb1, bufB, n);
  k_xform1<true>    <<<gn, b256, 0, stream>>>(bufB, gW2, s0, n);
  k_agg1_final      <<<gw, b256, 0, stream>>>(row, packed, s0, dinv, gb2, gWl, gbl, xsol, x, (float*)d_out, n);
}